// Round 5
// baseline (72.790 us; speedup 1.0000x reference)
//
#include <hip/hip_runtime.h>

#define D    64
#define NROW 8192

typedef _Float16 f16x8 __attribute__((ext_vector_type(8)));
typedef float    f32x4 __attribute__((ext_vector_type(4)));

// ---------------------------------------------------------------------------
// Pre-pass: split f32 inputs into f16 hi/lo planes ONCE, plus squared norms.
//   hi/lo: f16[16384][64]  (rows 0..8191 = x, 8192..16383 = y)
//   sq:    f32[16384]
// ---------------------------------------------------------------------------
__global__ __launch_bounds__(256) void rbf_split(const float* __restrict__ x,
                                                 const float* __restrict__ y,
                                                 _Float16* __restrict__ hi,
                                                 _Float16* __restrict__ lo,
                                                 float* __restrict__ sq) {
    const int tid    = blockIdx.x * 256 + threadIdx.x;  // 0..131071
    const int rowAll = tid >> 3;                        // 0..16383
    const int dp     = (tid & 7) * 8;
    const float* src = (rowAll < NROW) ? (x + (size_t)rowAll * D)
                                       : (y + (size_t)(rowAll - NROW) * D);
    float4 a0 = *reinterpret_cast<const float4*>(src + dp);
    float4 a1 = *reinterpret_cast<const float4*>(src + dp + 4);
    float v[8] = {a0.x, a0.y, a0.z, a0.w, a1.x, a1.y, a1.z, a1.w};
    f16x8 h, l;
    float s = 0.f;
#pragma unroll
    for (int j = 0; j < 8; ++j) {
        _Float16 hh = (_Float16)v[j];
        h[j] = hh;
        l[j] = (_Float16)(v[j] - (float)hh);
        s = fmaf(v[j], v[j], s);
    }
    *reinterpret_cast<f16x8*>(hi + (size_t)rowAll * D + dp) = h;
    *reinterpret_cast<f16x8*>(lo + (size_t)rowAll * D + dp) = l;
    s += __shfl_xor(s, 1);
    s += __shfl_xor(s, 2);
    s += __shfl_xor(s, 4);
    if ((tid & 7) == 0) sq[rowAll] = s;
}

// ---------------------------------------------------------------------------
// Main kernel (pre-split path): R3's verified MFMA structure + epilogue, all
// f32->f16 conversion removed. Staging bug from R4 fixed: each LDS row is
// 8 x 16-B chunks; 2 threads/row x 4 chunks each now cover all 128 B.
// ---------------------------------------------------------------------------
__global__ __launch_bounds__(256, 3) void rbf_main2(const _Float16* __restrict__ hi,
                                                    const _Float16* __restrict__ lo,
                                                    const float* __restrict__ sq,
                                                    float* __restrict__ out) {
    __shared__ __align__(16) char YH[16384];   // f16[128 rows][64 d], swizzled
    __shared__ __align__(16) char YL[16384];

    const int t    = threadIdx.x;
    const int col0 = blockIdx.x * 128;   // y-col tile
    const int row0 = blockIdx.y * 128;   // x-row tile

    // ---- stage pre-split y tile into swizzled LDS (pure copy) ------------
    {
        const int r   = t & 127;
        const int hb  = t >> 7;
        const int swz = (r & 7) << 4;
        const _Float16* gh = hi + (size_t)(NROW + col0 + r) * D;
        const _Float16* gl = lo + (size_t)(NROW + col0 + r) * D;
#pragma unroll
        for (int it = 0; it < 4; ++it) {
            const int c16 = hb * 4 + it;                 // 16-B chunk 0..7
            const int off = r * 128 + ((c16 * 16) ^ swz);
            *reinterpret_cast<f16x8*>(YH + off) =
                *reinterpret_cast<const f16x8*>(gh + c16 * 8);
            *reinterpret_cast<f16x8*>(YL + off) =
                *reinterpret_cast<const f16x8*>(gl + c16 * 8);
        }
    }

    // ---- x fragments: direct 16-B loads of pre-split data ----------------
    const int lane = t & 63;
    const int w    = t >> 6;        // wave id -> x-row strip w*32
    const int l15  = lane & 15;
    const int lg   = lane >> 4;     // k-slot group

    f16x8 xh[2][2], xl[2][2];       // [row sub-tile][k half]
    float xsq[2];
#pragma unroll
    for (int i = 0; i < 2; ++i) {
        const size_t xoff = (size_t)(row0 + w * 32 + i * 16 + l15) * D + lg * 8;
#pragma unroll
        for (int kh = 0; kh < 2; ++kh) {
            xh[i][kh] = *reinterpret_cast<const f16x8*>(hi + xoff + kh * 32);
            xl[i][kh] = *reinterpret_cast<const f16x8*>(lo + xoff + kh * 32);
        }
        xsq[i] = sq[row0 + w * 32 + i * 16 + l15];
    }
    __syncthreads();

    // ---- MFMA main: A = y (LDS), B = x (reg); 96 MFMAs / wave ------------
    f32x4 acc[2][8];
#pragma unroll
    for (int i = 0; i < 2; ++i)
#pragma unroll
        for (int nt = 0; nt < 8; ++nt) acc[i][nt] = (f32x4){0.f, 0.f, 0.f, 0.f};

    const int swzA = (l15 & 7) << 4;
#pragma unroll
    for (int kh = 0; kh < 2; ++kh) {
        const int dsw = (kh * 64 + lg * 16) ^ swzA;
#pragma unroll
        for (int nt = 0; nt < 8; ++nt) {
            const int aoff = (nt * 16 + l15) * 128 + dsw;
            f16x8 ah = *reinterpret_cast<const f16x8*>(YH + aoff);
            f16x8 al = *reinterpret_cast<const f16x8*>(YL + aoff);
            acc[0][nt] = __builtin_amdgcn_mfma_f32_16x16x32_f16(ah, xh[0][kh], acc[0][nt], 0, 0, 0);
            acc[1][nt] = __builtin_amdgcn_mfma_f32_16x16x32_f16(ah, xh[1][kh], acc[1][nt], 0, 0, 0);
            acc[0][nt] = __builtin_amdgcn_mfma_f32_16x16x32_f16(al, xh[0][kh], acc[0][nt], 0, 0, 0);
            acc[1][nt] = __builtin_amdgcn_mfma_f32_16x16x32_f16(al, xh[1][kh], acc[1][nt], 0, 0, 0);
            acc[0][nt] = __builtin_amdgcn_mfma_f32_16x16x32_f16(ah, xl[0][kh], acc[0][nt], 0, 0, 0);
            acc[1][nt] = __builtin_amdgcn_mfma_f32_16x16x32_f16(ah, xl[1][kh], acc[1][nt], 0, 0, 0);
        }
    }

    // ---- epilogue: dist^2 -> exp -> float4 stores (verified layout) ------
#pragma unroll
    for (int nt = 0; nt < 8; ++nt) {
        const int c = nt * 16 + lg * 4;
        float4 q = *reinterpret_cast<const float4*>(sq + NROW + col0 + c);
        float ysqv[4] = {q.x, q.y, q.z, q.w};
#pragma unroll
        for (int i = 0; i < 2; ++i) {
            const int rowg = row0 + w * 32 + i * 16 + l15;
            float e[4];
#pragma unroll
            for (int r = 0; r < 4; ++r) {
                float d2 = fmaf(-2.f, acc[i][nt][r], xsq[i] + ysqv[r]);
                d2 = fmaxf(d2, 0.f);
                e[r] = __expf(-d2);
            }
            *reinterpret_cast<float4*>(out + (size_t)rowg * NROW + col0 + c) =
                make_float4(e[0], e[1], e[2], e[3]);
        }
    }
}

// ---------------------------------------------------------------------------
// Fallback (R3, proven): fully fused, no workspace needed.
// ---------------------------------------------------------------------------
__global__ __launch_bounds__(256, 3) void rbf_fused(const float* __restrict__ x,
                                                    const float* __restrict__ y,
                                                    float* __restrict__ out) {
    __shared__ __align__(16) char YH[16384];
    __shared__ __align__(16) char YL[16384];
    __shared__ float Ysq0[128];
    __shared__ float Ysq1[128];

    const int t    = threadIdx.x;
    const int col0 = blockIdx.x * 128;
    const int row0 = blockIdx.y * 128;

    {
        const int r    = t & 127;
        const int half = t >> 7;
        const int swz  = (r & 7) << 4;
        const float* yp = y + (size_t)(col0 + r) * D + half * 32;
        float ssq = 0.f;
#pragma unroll
        for (int it = 0; it < 4; ++it) {
            float4 b0 = *reinterpret_cast<const float4*>(yp + it * 8);
            float4 b1 = *reinterpret_cast<const float4*>(yp + it * 8 + 4);
            float v[8] = {b0.x, b0.y, b0.z, b0.w, b1.x, b1.y, b1.z, b1.w};
            f16x8 h, l;
#pragma unroll
            for (int j = 0; j < 8; ++j) {
                _Float16 hh = (_Float16)v[j];
                h[j] = hh;
                l[j] = (_Float16)(v[j] - (float)hh);
                ssq  = fmaf(v[j], v[j], ssq);
            }
            const int off = r * 128 + ((half * 64 + it * 16) ^ swz);
            *reinterpret_cast<f16x8*>(YH + off) = h;
            *reinterpret_cast<f16x8*>(YL + off) = l;
        }
        if (half == 0) Ysq0[r] = ssq; else Ysq1[r] = ssq;
    }

    const int lane = t & 63;
    const int w    = t >> 6;
    const int l15  = lane & 15;
    const int lg   = lane >> 4;

    f16x8 xh[2][2], xl[2][2];
    float xsq[2];
#pragma unroll
    for (int i = 0; i < 2; ++i) {
        const float* xp = x + (size_t)(row0 + w * 32 + i * 16 + l15) * D + lg * 8;
        float s = 0.f;
#pragma unroll
        for (int kh = 0; kh < 2; ++kh) {
            float4 a0 = *reinterpret_cast<const float4*>(xp + kh * 32);
            float4 a1 = *reinterpret_cast<const float4*>(xp + kh * 32 + 4);
            float v[8] = {a0.x, a0.y, a0.z, a0.w, a1.x, a1.y, a1.z, a1.w};
#pragma unroll
            for (int j = 0; j < 8; ++j) {
                _Float16 hh = (_Float16)v[j];
                xh[i][kh][j] = hh;
                xl[i][kh][j] = (_Float16)(v[j] - (float)hh);
                s = fmaf(v[j], v[j], s);
            }
        }
        s += __shfl_xor(s, 16);
        s += __shfl_xor(s, 32);
        xsq[i] = s;
    }
    __syncthreads();

    f32x4 acc[2][8];
#pragma unroll
    for (int i = 0; i < 2; ++i)
#pragma unroll
        for (int nt = 0; nt < 8; ++nt) acc[i][nt] = (f32x4){0.f, 0.f, 0.f, 0.f};

    const int swzA = (l15 & 7) << 4;
#pragma unroll
    for (int kh = 0; kh < 2; ++kh) {
        const int dsw = (kh * 64 + lg * 16) ^ swzA;
#pragma unroll
        for (int nt = 0; nt < 8; ++nt) {
            const int aoff = (nt * 16 + l15) * 128 + dsw;
            f16x8 yh = *reinterpret_cast<const f16x8*>(YH + aoff);
            f16x8 yl = *reinterpret_cast<const f16x8*>(YL + aoff);
            acc[0][nt] = __builtin_amdgcn_mfma_f32_16x16x32_f16(yh, xh[0][kh], acc[0][nt], 0, 0, 0);
            acc[1][nt] = __builtin_amdgcn_mfma_f32_16x16x32_f16(yh, xh[1][kh], acc[1][nt], 0, 0, 0);
            acc[0][nt] = __builtin_amdgcn_mfma_f32_16x16x32_f16(yl, xh[0][kh], acc[0][nt], 0, 0, 0);
            acc[1][nt] = __builtin_amdgcn_mfma_f32_16x16x32_f16(yl, xh[1][kh], acc[1][nt], 0, 0, 0);
            acc[0][nt] = __builtin_amdgcn_mfma_f32_16x16x32_f16(yh, xl[0][kh], acc[0][nt], 0, 0, 0);
            acc[1][nt] = __builtin_amdgcn_mfma_f32_16x16x32_f16(yh, xl[1][kh], acc[1][nt], 0, 0, 0);
        }
    }

#pragma unroll
    for (int nt = 0; nt < 8; ++nt) {
        const int c = nt * 16 + lg * 4;
        float4 p0 = *reinterpret_cast<const float4*>(&Ysq0[c]);
        float4 p1 = *reinterpret_cast<const float4*>(&Ysq1[c]);
        float ysqv[4] = {p0.x + p1.x, p0.y + p1.y, p0.z + p1.z, p0.w + p1.w};
#pragma unroll
        for (int i = 0; i < 2; ++i) {
            const int rowg = row0 + w * 32 + i * 16 + l15;
            float e[4];
#pragma unroll
            for (int r = 0; r < 4; ++r) {
                float d2 = fmaf(-2.f, acc[i][nt][r], xsq[i] + ysqv[r]);
                d2 = fmaxf(d2, 0.f);
                e[r] = __expf(-d2);
            }
            *reinterpret_cast<float4*>(out + (size_t)rowg * NROW + col0 + c) =
                make_float4(e[0], e[1], e[2], e[3]);
        }
    }
}

extern "C" void kernel_launch(void* const* d_in, const int* in_sizes, int n_in,
                              void* d_out, int out_size, void* d_ws, size_t ws_size,
                              hipStream_t stream) {
    const float* x = (const float*)d_in[0];
    const float* y = (const float*)d_in[1];
    float* out = (float*)d_out;

    const size_t planeElems = (size_t)2 * NROW * D;              // 16384*64
    const size_t need = planeElems * sizeof(_Float16) * 2        // hi + lo
                      + (size_t)2 * NROW * sizeof(float);        // sq
    if (ws_size >= need) {
        _Float16* hi = (_Float16*)d_ws;
        _Float16* lo = hi + planeElems;
        float* sq    = (float*)(lo + planeElems);
        rbf_split<<<512, 256, 0, stream>>>(x, y, hi, lo, sq);
        rbf_main2<<<dim3(NROW / 128, NROW / 128), 256, 0, stream>>>(hi, lo, sq, out);
    } else {
        rbf_fused<<<dim3(NROW / 128, NROW / 128), 256, 0, stream>>>(x, y, out);
    }
}

// Round 6
// 70.069 us; speedup vs baseline: 1.0388x; 1.0388x over previous
//
#include <hip/hip_runtime.h>

#define D    64
#define NROW 8192

typedef _Float16 f16x8 __attribute__((ext_vector_type(8)));
typedef float    f32x4 __attribute__((ext_vector_type(4)));

// ---------------------------------------------------------------------------
// Fused RBF kernel (R3 base + transposed linear-store epilogue).
// 128x128 tile, 256 threads (4 waves).
//   - y tile staged in LDS as f16 hi/lo split (XOR-swizzled) + partial ysq.
//   - x fragments direct from global, split in-register; xsq via shfl_xor.
//   - MFMA swapped operands (verified): lane's 4 acc regs = 4 consecutive
//     y-cols.
//   - NEW epilogue: exp in place -> f32 tile through LDS (reuse Y buffers,
//     wave-private regions) -> row-linear 256-B-contiguous nontemporal
//     stores (vs 64-B scattered segments before).
// ---------------------------------------------------------------------------
__global__ __launch_bounds__(256, 3) void rbf_fused(const float* __restrict__ x,
                                                    const float* __restrict__ y,
                                                    float* __restrict__ out) {
    __shared__ __align__(16) char smem[32768];   // YH|YL, then f32 stage S
    __shared__ float Ysq0[128];
    __shared__ float Ysq1[128];
    char* const YH = smem;
    char* const YL = smem + 16384;

    const int t    = threadIdx.x;
    const int col0 = blockIdx.x * 128;   // y-col tile
    const int row0 = blockIdx.y * 128;   // x-row tile

    // ---- stage y tile: hi/lo split + partial squared norms ---------------
    {
        const int r    = t & 127;
        const int half = t >> 7;                 // d-halves 0..31 / 32..63
        const int swz  = (r & 7) << 4;
        const float* yp = y + (size_t)(col0 + r) * D + half * 32;
        float ssq = 0.f;
#pragma unroll
        for (int it = 0; it < 4; ++it) {
            float4 b0 = *reinterpret_cast<const float4*>(yp + it * 8);
            float4 b1 = *reinterpret_cast<const float4*>(yp + it * 8 + 4);
            float v[8] = {b0.x, b0.y, b0.z, b0.w, b1.x, b1.y, b1.z, b1.w};
            f16x8 h, l;
#pragma unroll
            for (int j = 0; j < 8; ++j) {
                _Float16 hh = (_Float16)v[j];
                h[j] = hh;
                l[j] = (_Float16)(v[j] - (float)hh);
                ssq  = fmaf(v[j], v[j], ssq);
            }
            const int off = r * 128 + ((half * 64 + it * 16) ^ swz);
            *reinterpret_cast<f16x8*>(YH + off) = h;
            *reinterpret_cast<f16x8*>(YL + off) = l;
        }
        if (half == 0) Ysq0[r] = ssq; else Ysq1[r] = ssq;
    }

    // ---- x fragments direct from global, split in-register ---------------
    const int lane = t & 63;
    const int w    = t >> 6;        // wave id -> x-row strip w*32
    const int l15  = lane & 15;
    const int lg   = lane >> 4;     // k-slot group

    f16x8 xh[2][2], xl[2][2];       // [row sub-tile][k half]
    float xsq[2];
#pragma unroll
    for (int i = 0; i < 2; ++i) {
        const float* xp = x + (size_t)(row0 + w * 32 + i * 16 + l15) * D + lg * 8;
        float s = 0.f;
#pragma unroll
        for (int kh = 0; kh < 2; ++kh) {
            float4 a0 = *reinterpret_cast<const float4*>(xp + kh * 32);
            float4 a1 = *reinterpret_cast<const float4*>(xp + kh * 32 + 4);
            float v[8] = {a0.x, a0.y, a0.z, a0.w, a1.x, a1.y, a1.z, a1.w};
#pragma unroll
            for (int j = 0; j < 8; ++j) {
                _Float16 hh = (_Float16)v[j];
                xh[i][kh][j] = hh;
                xl[i][kh][j] = (_Float16)(v[j] - (float)hh);
                s = fmaf(v[j], v[j], s);
            }
        }
        s += __shfl_xor(s, 16);
        s += __shfl_xor(s, 32);
        xsq[i] = s;
    }
    __syncthreads();

    // ---- MFMA main: A = y (LDS), B = x (reg); 96 MFMAs / wave ------------
    f32x4 acc[2][8];
#pragma unroll
    for (int i = 0; i < 2; ++i)
#pragma unroll
        for (int nt = 0; nt < 8; ++nt) acc[i][nt] = (f32x4){0.f, 0.f, 0.f, 0.f};

    const int swzA = (l15 & 7) << 4;
#pragma unroll
    for (int kh = 0; kh < 2; ++kh) {
        const int dsw = (kh * 64 + lg * 16) ^ swzA;
#pragma unroll
        for (int nt = 0; nt < 8; ++nt) {
            const int aoff = (nt * 16 + l15) * 128 + dsw;
            f16x8 yh = *reinterpret_cast<const f16x8*>(YH + aoff);
            f16x8 yl = *reinterpret_cast<const f16x8*>(YL + aoff);
            acc[0][nt] = __builtin_amdgcn_mfma_f32_16x16x32_f16(yh, xh[0][kh], acc[0][nt], 0, 0, 0);
            acc[1][nt] = __builtin_amdgcn_mfma_f32_16x16x32_f16(yh, xh[1][kh], acc[1][nt], 0, 0, 0);
            acc[0][nt] = __builtin_amdgcn_mfma_f32_16x16x32_f16(yl, xh[0][kh], acc[0][nt], 0, 0, 0);
            acc[1][nt] = __builtin_amdgcn_mfma_f32_16x16x32_f16(yl, xh[1][kh], acc[1][nt], 0, 0, 0);
            acc[0][nt] = __builtin_amdgcn_mfma_f32_16x16x32_f16(yh, xl[0][kh], acc[0][nt], 0, 0, 0);
            acc[1][nt] = __builtin_amdgcn_mfma_f32_16x16x32_f16(yh, xl[1][kh], acc[1][nt], 0, 0, 0);
        }
    }

    // ---- exp in place (before LDS reuse; Ysq/YH/YL reads all done after
    //      this loop + barrier) --------------------------------------------
#pragma unroll
    for (int nt = 0; nt < 8; ++nt) {
        const int c = nt * 16 + lg * 4;
        float4 p0 = *reinterpret_cast<const float4*>(&Ysq0[c]);
        float4 p1 = *reinterpret_cast<const float4*>(&Ysq1[c]);
        float ys[4] = {p0.x + p1.x, p0.y + p1.y, p0.z + p1.z, p0.w + p1.w};
#pragma unroll
        for (int i = 0; i < 2; ++i) {
#pragma unroll
            for (int r = 0; r < 4; ++r) {
                float d2 = fmaxf(fmaf(-2.f, acc[i][nt][r], xsq[i] + ys[r]), 0.f);
                acc[i][nt][r] = __expf(-d2);
            }
        }
    }
    __syncthreads();   // all waves done reading YH/YL (MFMA) before reuse

    // ---- transposed store: acc -> LDS f32 stage -> row-linear stores -----
    // S = f32[128 rows][64 cols] overlaid on YH|YL (32 KiB). Each wave only
    // touches its own 32-row strip -> no cross-wave barriers; in-wave DS
    // ordering + compiler lgkmcnt handle write->read.
    // Swizzle: 16-B chunk XOR (row&15)<<4, identical on write and read.
    char* const S = smem;
#pragma unroll
    for (int p = 0; p < 2; ++p) {          // col halves 0..63 / 64..127
#pragma unroll
        for (int k = 0; k < 4; ++k) {      // nt = p*4 + k
#pragma unroll
            for (int i = 0; i < 2; ++i) {
                const int row = w * 32 + i * 16 + l15;
                const int off = row * 256 + ((k * 64 + lg * 16) ^ ((row & 15) << 4));
                *reinterpret_cast<f32x4*>(S + off) = acc[i][p * 4 + k];
            }
        }
#pragma unroll
        for (int it = 0; it < 8; ++it) {
            const int rloc = w * 32 + it * 4 + (lane >> 4);
            const int off  = rloc * 256 + ((l15 * 16) ^ ((rloc & 15) << 4));
            f32x4 v = *reinterpret_cast<const f32x4*>(S + off);
            __builtin_nontemporal_store(v,
                reinterpret_cast<f32x4*>(out + (size_t)(row0 + rloc) * NROW
                                             + col0 + p * 64 + l15 * 4));
        }
    }
}

extern "C" void kernel_launch(void* const* d_in, const int* in_sizes, int n_in,
                              void* d_out, int out_size, void* d_ws, size_t ws_size,
                              hipStream_t stream) {
    const float* x = (const float*)d_in[0];
    const float* y = (const float*)d_in[1];
    float* out = (float*)d_out;
    (void)d_ws; (void)ws_size;

    rbf_fused<<<dim3(NROW / 128, NROW / 128), 256, 0, stream>>>(x, y, out);
}